// Round 4
// baseline (639.320 us; speedup 1.0000x reference)
//
#include <hip/hip_runtime.h>
#include <hip/hip_bf16.h>
#include <math.h>
#include <stdint.h>

typedef __bf16 bf16_t;
typedef bf16_t bf16x4 __attribute__((ext_vector_type(4)));
typedef bf16_t bf16x8 __attribute__((ext_vector_type(8)));
typedef float floatx4 __attribute__((ext_vector_type(4)));

#define B_     4
#define S_     4096
#define D_     1024
#define P_     1364
#define P3_    4092      // 3*P
#define NP_    5456      // 3P + P
#define NB_    5632      // GEMM1 N padded to 22 tiles of 256
#define PR_    1368      // per-gate section stride (8-mult -> 16B aligned)
#define ACT_LD_ 5472     // act row stride = 4*PR_
#define KPAD_  1408      // P_ padded (K of out-GEMM, 22 K-tiles)
#define ROWS_  16384     // B*S
#define CAP_   15.0f
#define EPS_   1e-6f
#define CHUNKS_ 64
#define CLEN_   64       // S_/CHUNKS_

// ---------------- fast transcendentals (bf16-accuracy) ----------------
__device__ __forceinline__ float fast_tanh(float x) {
    x = fminf(fmaxf(x, -15.f), 15.f);
    float e = __expf(2.f * x);
    return __fdividef(e - 1.f, e + 1.f);
}
__device__ __forceinline__ float fast_softcap_sig(float g) {
    float t = fast_tanh(g * (1.0f / CAP_));
    return __fdividef(1.f, 1.f + __expf(-CAP_ * t));
}

template <int N>
__device__ __forceinline__ void vmcnt_wait() {
    if constexpr (N == 8)      asm volatile("s_waitcnt vmcnt(8)" ::: "memory");
    else if constexpr (N == 0) asm volatile("s_waitcnt vmcnt(0)" ::: "memory");
}

// ---------------- RMSNorm: x fp32 [ROWS][D] -> xn bf16 [ROWS][D] ----------------
__global__ __launch_bounds__(256) void rmsnorm_kernel(const float* __restrict__ x,
                                                      const float* __restrict__ w,
                                                      bf16_t* __restrict__ xn) {
    int row = blockIdx.x;
    int tid = threadIdx.x;
    const float4 v = ((const float4*)(x + (size_t)row * D_))[tid];
    float ss = v.x * v.x + v.y * v.y + v.z * v.z + v.w * v.w;
    #pragma unroll
    for (int off = 32; off > 0; off >>= 1) ss += __shfl_down(ss, off);
    __shared__ float red[4];
    if ((tid & 63) == 0) red[tid >> 6] = ss;
    __syncthreads();
    float tot = red[0] + red[1] + red[2] + red[3];
    float scale = rsqrtf(tot * (1.0f / (float)D_) + EPS_);
    const float4 wv = ((const float4*)w)[tid];
    bf16x4 o;
    o[0] = (bf16_t)(v.x * scale * wv.x);
    o[1] = (bf16_t)(v.y * scale * wv.y);
    o[2] = (bf16_t)(v.z * scale * wv.z);
    o[3] = (bf16_t)(v.w * scale * wv.w);
    ((bf16x4*)(xn + (size_t)row * D_))[tid] = o;
}

// ---- pack W_gate [D][3P] + W_cell [D][P] fp32 -> Wcat^T bf16 [NB_][D] ----
__global__ __launch_bounds__(256) void pack_wcat(const float* __restrict__ Wg,
                                                 const float* __restrict__ Wc,
                                                 bf16_t* __restrict__ Wt) {
    __shared__ float tile[32][33];
    int kt = blockIdx.x * 32;
    int nt = blockIdx.y * 32;
    int tx = threadIdx.x & 31;
    int ty = threadIdx.x >> 5;
    #pragma unroll
    for (int i = 0; i < 4; i++) {
        int k = kt + ty + 8 * i;
        int n = nt + tx;
        float val = 0.f;
        if (n < P3_)      val = Wg[(size_t)k * P3_ + n];
        else if (n < NP_) val = Wc[(size_t)k * P_ + (n - P3_)];
        tile[ty + 8 * i][tx] = val;
    }
    __syncthreads();
    #pragma unroll
    for (int i = 0; i < 4; i++) {
        int n = nt + ty + 8 * i;
        int k = kt + tx;
        Wt[(size_t)n * D_ + k] = (bf16_t)tile[tx][ty + 8 * i];
    }
}

// ---- pack W_out [P][D] fp32 -> Wout^T bf16 [D][KPAD_] ----
__global__ __launch_bounds__(256) void pack_wout(const float* __restrict__ Wo,
                                                 bf16_t* __restrict__ Wt) {
    __shared__ float tile[32][33];
    int pt = blockIdx.x * 32;
    int dt = blockIdx.y * 32;
    int tx = threadIdx.x & 31;
    int ty = threadIdx.x >> 5;
    #pragma unroll
    for (int i = 0; i < 4; i++) {
        int p = pt + ty + 8 * i;
        int d = dt + tx;
        float val = (p < P_) ? Wo[(size_t)p * D_ + d] : 0.f;
        tile[ty + 8 * i][tx] = val;
    }
    __syncthreads();
    #pragma unroll
    for (int i = 0; i < 4; i++) {
        int d = dt + ty + 8 * i;
        int p = pt + tx;
        Wt[(size_t)d * KPAD_ + p] = (bf16_t)tile[tx][ty + 8 * i];
    }
}

// ---------------- 256x256 8-wave GEMM: 2 barriers/K-tile, free compute region ----------------
// LDS: buf b: A at b*65536 + kk*16384, B at +32768. Zero-conflict swizzle (verified r3):
// read slot sp = sl4 ^ ((lane>>1)&3); stage source chunk = (lane&3)^((lane>>3)&3).
// Per tile: [region: 24 ds_read + 64 MFMA, compiler-scheduled] barrier;
//           stage(t+2); vmcnt(8); barrier.  (counted vmcnt, never 0 mid-loop)
template <int KTOT, int LDA, int LDB, int LDC, int NX, int EPI>
__global__ __launch_bounds__(512, 2) void gemm8(const bf16_t* __restrict__ A,
                                                const bf16_t* __restrict__ Bt,
                                                const float* __restrict__ res,
                                                void* __restrict__ outv) {
    constexpr int NT = KTOT / 64;
    static_assert(NT >= 4, "NT >= 4");
    __shared__ __align__(16) char smem[131072];

    const int tid  = threadIdx.x;
    const int wid  = tid >> 6;
    const int lane = tid & 63;
    const int l15  = lane & 15;
    const int sl4  = lane >> 4;
    const int sp    = sl4 ^ ((lane >> 1) & 3);
    const int chunk = (lane & 3) ^ ((lane >> 3) & 3);
    const int wrow = (wid >> 2) * 128;
    const int wcol = (wid & 3) * 64;

    // XCD mapping: each XCD owns 8 by-rows, iterates bx-OUTER (B-panel L2-resident)
    constexpr int MB  = ROWS_ / 256;   // 64
    constexpr int MCH = MB / 8;        // 8 by-rows per XCD
    const int bid = blockIdx.x;
    const int xcd = bid & 7;
    const int idx = bid >> 3;
    const int bx  = idx / MCH;
    const int by  = xcd * MCH + (idx - bx * MCH);
    const int m0 = by * 256, n0 = bx * 256;

    const int srow = wid * 16 + (lane >> 2);
    const bf16_t* Asrc = A  + (size_t)(m0 + srow) * LDA + chunk * 8;
    const bf16_t* Bsrc = Bt + (size_t)(n0 + srow) * LDB + chunk * 8;
    const unsigned ldsA0 = (unsigned)(wid * 1024);
    const unsigned ldsB0 = 32768u + (unsigned)(wid * 1024);

    auto stage = [&](int kt, int buf) {  // 8 global_load_lds per wave
        #pragma unroll
        for (int kk = 0; kk < 2; kk++) {
            const bf16_t* sa = Asrc + kt * 64 + kk * 32;
            char* da = smem + ((unsigned)buf * 65536u + (unsigned)kk * 16384u + ldsA0);
            __builtin_amdgcn_global_load_lds((const unsigned*)sa, (unsigned*)da, 16, 0, 0);
            __builtin_amdgcn_global_load_lds((const unsigned*)(sa + (size_t)128 * LDA),
                                             (unsigned*)(da + 8192), 16, 0, 0);
            const bf16_t* sb = Bsrc + kt * 64 + kk * 32;
            char* db = smem + ((unsigned)buf * 65536u + (unsigned)kk * 16384u + ldsB0);
            __builtin_amdgcn_global_load_lds((const unsigned*)sb, (unsigned*)db, 16, 0, 0);
            __builtin_amdgcn_global_load_lds((const unsigned*)(sb + (size_t)128 * LDB),
                                             (unsigned*)(db + 8192), 16, 0, 0);
        }
    };
    auto ldA = [&](int buf, int kk, int m) -> bf16x8 {
        return *(const bf16x8*)(smem + (buf * 65536 + kk * 16384 +
                                        (wrow + m * 16 + l15) * 64 + sp * 16));
    };
    auto ldB = [&](int buf, int kk, int n) -> bf16x8 {
        return *(const bf16x8*)(smem + (buf * 65536 + 32768 + kk * 16384 +
                                        (wcol + n * 16 + l15) * 64 + sp * 16));
    };

    floatx4 acc[8][4];
    #pragma unroll
    for (int m = 0; m < 8; m++)
        #pragma unroll
        for (int n = 0; n < 4; n++) acc[m][n] = (floatx4){0.f, 0.f, 0.f, 0.f};

    auto compute_tile = [&](int buf) {
        bf16x8 a[8], bb[4];
        #pragma unroll
        for (int kk = 0; kk < 2; kk++) {
            #pragma unroll
            for (int m = 0; m < 8; m++) a[m] = ldA(buf, kk, m);
            #pragma unroll
            for (int n = 0; n < 4; n++) bb[n] = ldB(buf, kk, n);
            #pragma unroll
            for (int m = 0; m < 8; m++)
                #pragma unroll
                for (int n = 0; n < 4; n++)
                    acc[m][n] = __builtin_amdgcn_mfma_f32_16x16x32_bf16(a[m], bb[n], acc[m][n], 0, 0, 0);
        }
    };

    // prologue: tiles 0,1 staged (16 loads; first 8 = tile0)
    stage(0, 0);
    stage(1, 1);
    vmcnt_wait<8>();
    __builtin_amdgcn_s_barrier();

    #pragma unroll 2
    for (int t = 0; t < NT - 1; ++t) {
        const int cur = t & 1;
        __builtin_amdgcn_s_setprio(1);
        compute_tile(cur);
        __builtin_amdgcn_s_setprio(0);
        __builtin_amdgcn_s_barrier();              // all waves done reading buf[cur]
        if (t + 2 < NT) {
            stage(t + 2, cur);                     // refill freed buffer
            vmcnt_wait<8>();                       // retire tile t+1's 8 loads
        } else {
            vmcnt_wait<0>();
        }
        __builtin_amdgcn_s_barrier();              // buf[cur^1] ready for all
    }
    __builtin_amdgcn_s_setprio(1);
    compute_tile((NT - 1) & 1);
    __builtin_amdgcn_s_setprio(0);

    const int crow = m0 + wrow + sl4 * 4;
    const int ccol = n0 + wcol + l15;
    if constexpr (EPI == 0) {
        // act layout: gate g section at g*PR_, row stride LDC(=ACT_LD_)
        bf16_t* O = (bf16_t*)outv;
        #pragma unroll
        for (int m = 0; m < 8; m++)
            #pragma unroll
            for (int n = 0; n < 4; n++) {
                const int col = ccol + n * 16;
                if (col < NP_) {
                    const int g  = (col >= P3_) ? 3 : col / P_;
                    const int pp = col - g * P_;
                    const size_t cb = (size_t)g * PR_ + pp;
                    #pragma unroll
                    for (int r = 0; r < 4; r++) {
                        const int row = crow + m * 16 + r;
                        float gg = acc[m][n][r];
                        float v = (g < 3) ? fast_softcap_sig(gg) : fast_tanh(gg);
                        O[(size_t)row * LDC + cb] = (bf16_t)v;
                    }
                }
            }
    } else {
        float* O = (float*)outv;
        #pragma unroll
        for (int m = 0; m < 8; m++)
            #pragma unroll
            for (int n = 0; n < 4; n++) {
                const int col = ccol + n * 16;
                #pragma unroll
                for (int r = 0; r < 4; r++) {
                    const int row = crow + m * 16 + r;
                    O[(size_t)row * LDC + col] = res[(size_t)row * LDC + col] + acc[m][n][r];
                }
            }
    }
}

// ---------------- chunked linear recurrence (vectorized x8) ----------------
// act row: i @0, f @PR_, o @2*PR_, tanh(c) @3*PR_ (each 16B-aligned section)
__global__ __launch_bounds__(256) void chunk_scan1(const bf16_t* __restrict__ act,
                                                   float* __restrict__ FA) {
    int p8 = (blockIdx.x * 256 + threadIdx.x) * 8;
    if (p8 >= P_) return;
    int c = blockIdx.y, b = blockIdx.z;
    const bf16_t* base = act + (size_t)(b * S_ + c * CLEN_) * ACT_LD_;
    float F[8], Ac[8];
    #pragma unroll
    for (int e = 0; e < 8; e++) { F[e] = 1.f; Ac[e] = 0.f; }
    if (p8 + 8 <= P_) {
        for (int t = 0; t < CLEN_; t++) {
            const bf16_t* r = base + (size_t)t * ACT_LD_;
            bf16x8 iv = *(const bf16x8*)(r + p8);
            bf16x8 fv = *(const bf16x8*)(r + PR_ + p8);
            bf16x8 tc = *(const bf16x8*)(r + 3 * PR_ + p8);
            #pragma unroll
            for (int e = 0; e < 8; e++) {
                float f = (float)fv[e];
                Ac[e] = f * Ac[e] + (float)iv[e] * (float)tc[e];
                F[e] *= f;
            }
        }
    } else {
        for (int t = 0; t < CLEN_; t++) {
            const bf16_t* r = base + (size_t)t * ACT_LD_;
            #pragma unroll
            for (int e = 0; e < 8; e++) {
                int p = p8 + e;
                if (p < P_) {
                    float f = (float)r[PR_ + p];
                    Ac[e] = f * Ac[e] + (float)r[p] * (float)r[3 * PR_ + p];
                    F[e] *= f;
                }
            }
        }
    }
    #pragma unroll
    for (int e = 0; e < 8; e++) {
        int p = p8 + e;
        if (p < P_) {
            size_t idx = (((size_t)b * CHUNKS_ + c) * P_ + p) * 2;
            FA[idx] = F[e]; FA[idx + 1] = Ac[e];
        }
    }
}

__global__ __launch_bounds__(256) void chunk_scan2(const bf16_t* __restrict__ act,
                                                   const float* __restrict__ FA,
                                                   const float* __restrict__ h0,
                                                   bf16_t* __restrict__ outp) {
    int p8 = (blockIdx.x * 256 + threadIdx.x) * 8;
    if (p8 >= KPAD_) return;
    int c = blockIdx.y, b = blockIdx.z;
    bf16_t* ob = outp + (size_t)(b * S_ + c * CLEN_) * KPAD_;
    if (p8 >= P_) {  // fully-pad vector: zero-fill
        bf16x8 z;
        #pragma unroll
        for (int e = 0; e < 8; e++) z[e] = (bf16_t)0.f;
        for (int t = 0; t < CLEN_; t++)
            *(bf16x8*)(ob + (size_t)t * KPAD_ + p8) = z;
        return;
    }
    float h[8];
    #pragma unroll
    for (int e = 0; e < 8; e++) {
        int p = p8 + e;
        h[e] = (p < P_) ? h0[(size_t)b * P_ + p] : 0.f;
    }
    for (int j = 0; j < c; j++) {
        #pragma unroll
        for (int e = 0; e < 8; e++) {
            int p = p8 + e;
            if (p < P_) {
                size_t idx = (((size_t)b * CHUNKS_ + j) * P_ + p) * 2;
                h[e] = FA[idx + 1] + FA[idx] * h[e];
            }
        }
    }
    const bf16_t* base = act + (size_t)(b * S_ + c * CLEN_) * ACT_LD_;
    if (p8 + 8 <= P_) {
        for (int t = 0; t < CLEN_; t++) {
            const bf16_t* r = base + (size_t)t * ACT_LD_;
            bf16x8 iv = *(const bf16x8*)(r + p8);
            bf16x8 fv = *(const bf16x8*)(r + PR_ + p8);
            bf16x8 ov = *(const bf16x8*)(r + 2 * PR_ + p8);
            bf16x8 tc = *(const bf16x8*)(r + 3 * PR_ + p8);
            bf16x8 o;
            #pragma unroll
            for (int e = 0; e < 8; e++) {
                h[e] = (float)fv[e] * h[e] + (float)iv[e] * (float)tc[e];
                o[e] = (bf16_t)((float)ov[e] * fast_tanh(h[e]));
            }
            *(bf16x8*)(ob + (size_t)t * KPAD_ + p8) = o;
        }
    } else {
        for (int t = 0; t < CLEN_; t++) {
            const bf16_t* r = base + (size_t)t * ACT_LD_;
            #pragma unroll
            for (int e = 0; e < 8; e++) {
                int p = p8 + e;
                bf16_t val = (bf16_t)0.f;
                if (p < P_) {
                    h[e] = (float)r[PR_ + p] * h[e] + (float)r[p] * (float)r[3 * PR_ + p];
                    val = (bf16_t)((float)r[2 * PR_ + p] * fast_tanh(h[e]));
                }
                ob[(size_t)t * KPAD_ + p] = val;
            }
        }
    }
}

__global__ void copy_hidden(const float* __restrict__ hs, float* __restrict__ dst) {
    int i = blockIdx.x * 256 + threadIdx.x;
    if (i < B_ * P_) dst[i] = hs[i];
}

extern "C" void kernel_launch(void* const* d_in, const int* in_sizes, int n_in,
                              void* d_out, int out_size, void* d_ws, size_t ws_size,
                              hipStream_t stream) {
    const float* x   = (const float*)d_in[0];
    const float* hs  = (const float*)d_in[1];
    const float* lnw = (const float*)d_in[2];
    const float* Wg  = (const float*)d_in[3];
    const float* Wc  = (const float*)d_in[4];
    const float* Wo  = (const float*)d_in[5];
    float* out = (float*)d_out;

    char* ws = (char*)d_ws;
    size_t off = 0;
    auto alloc = [&](size_t bytes) {
        void* p = ws + off;
        off += (bytes + 255) & ~(size_t)255;
        return p;
    };
    bf16_t* xn_outp = (bf16_t*)alloc((size_t)ROWS_ * KPAD_ * 2);    // xn then outputs
    bf16_t* act     = (bf16_t*)alloc((size_t)ROWS_ * ACT_LD_ * 2);  // 179 MB
    bf16_t* WcatT   = (bf16_t*)alloc((size_t)NB_ * D_ * 2);
    bf16_t* WoutT   = (bf16_t*)alloc((size_t)D_ * KPAD_ * 2);
    float*  FA      = (float*)alloc((size_t)B_ * CHUNKS_ * P_ * 2 * 4);

    bf16_t* xn   = xn_outp;
    bf16_t* outp = xn_outp;

    hipLaunchKernelGGL(rmsnorm_kernel, dim3(ROWS_), dim3(256), 0, stream, x, lnw, xn);
    hipLaunchKernelGGL(pack_wcat, dim3(32, NB_ / 32), dim3(256), 0, stream, Wg, Wc, WcatT);
    hipLaunchKernelGGL(pack_wout, dim3(KPAD_ / 32, D_ / 32), dim3(256), 0, stream, Wo, WoutT);

    hipLaunchKernelGGL((gemm8<D_, D_, D_, ACT_LD_, NB_ / 256, 0>),
                       dim3((NB_ / 256) * (ROWS_ / 256)), dim3(512), 0, stream,
                       xn, WcatT, (const float*)nullptr, (void*)act);

    hipLaunchKernelGGL(chunk_scan1, dim3(1, CHUNKS_, B_), dim3(256), 0, stream, act, FA);
    hipLaunchKernelGGL(chunk_scan2, dim3(1, CHUNKS_, B_), dim3(256), 0, stream, act, FA, hs, outp);

    hipLaunchKernelGGL((gemm8<KPAD_, KPAD_, KPAD_, D_, D_ / 256, 1>),
                       dim3((D_ / 256) * (ROWS_ / 256)), dim3(512), 0, stream,
                       outp, WoutT, x, d_out);

    hipLaunchKernelGGL(copy_hidden, dim3((B_ * P_ + 255) / 256), dim3(256), 0, stream,
                       hs, out + (size_t)ROWS_ * D_);
}

// Round 5
// 501.635 us; speedup vs baseline: 1.2745x; 1.2745x over previous
//
#include <hip/hip_runtime.h>
#include <hip/hip_bf16.h>
#include <math.h>
#include <stdint.h>

typedef __bf16 bf16_t;
typedef bf16_t bf16x4 __attribute__((ext_vector_type(4)));
typedef bf16_t bf16x8 __attribute__((ext_vector_type(8)));
typedef float floatx4 __attribute__((ext_vector_type(4)));

#define B_     4
#define S_     4096
#define D_     1024
#define P_     1364
#define P3_    4092      // 3*P
#define NP_    5456      // 3P + P
#define NPAD_  5504      // act row stride
#define NB_    5632      // GEMM1 N padded to 22 tiles of 256
#define KPAD_  1408      // P_ padded (K of out-GEMM, 22 K-tiles)
#define ROWS_  16384     // B*S
#define CAP_   15.0f
#define EPS_   1e-6f
#define CHUNKS_ 32
#define CLEN_   128      // S_/CHUNKS_

// ---------------- fast transcendentals (bf16-accuracy) ----------------
__device__ __forceinline__ float fast_tanh(float x) {
    x = fminf(fmaxf(x, -15.f), 15.f);
    float e = __expf(2.f * x);
    return __fdividef(e - 1.f, e + 1.f);
}
__device__ __forceinline__ float fast_softcap_sig(float g) {
    float t = fast_tanh(g * (1.0f / CAP_));
    return __fdividef(1.f, 1.f + __expf(-CAP_ * t));
}

template <int N>
__device__ __forceinline__ void vmcnt_wait() {
    if constexpr (N == 8)      asm volatile("s_waitcnt vmcnt(8)" ::: "memory");
    else if constexpr (N == 0) asm volatile("s_waitcnt vmcnt(0)" ::: "memory");
}

// ---------------- RMSNorm: x fp32 [ROWS][D] -> xn bf16 [ROWS][D] ----------------
__global__ __launch_bounds__(256) void rmsnorm_kernel(const float* __restrict__ x,
                                                      const float* __restrict__ w,
                                                      bf16_t* __restrict__ xn) {
    int row = blockIdx.x;
    int tid = threadIdx.x;
    const float4 v = ((const float4*)(x + (size_t)row * D_))[tid];
    float ss = v.x * v.x + v.y * v.y + v.z * v.z + v.w * v.w;
    #pragma unroll
    for (int off = 32; off > 0; off >>= 1) ss += __shfl_down(ss, off);
    __shared__ float red[4];
    if ((tid & 63) == 0) red[tid >> 6] = ss;
    __syncthreads();
    float tot = red[0] + red[1] + red[2] + red[3];
    float scale = rsqrtf(tot * (1.0f / (float)D_) + EPS_);
    const float4 wv = ((const float4*)w)[tid];
    bf16x4 o;
    o[0] = (bf16_t)(v.x * scale * wv.x);
    o[1] = (bf16_t)(v.y * scale * wv.y);
    o[2] = (bf16_t)(v.z * scale * wv.z);
    o[3] = (bf16_t)(v.w * scale * wv.w);
    ((bf16x4*)(xn + (size_t)row * D_))[tid] = o;
}

// ---- pack W_gate [D][3P] + W_cell [D][P] fp32 -> Wcat^T bf16 [NB_][D] ----
__global__ __launch_bounds__(256) void pack_wcat(const float* __restrict__ Wg,
                                                 const float* __restrict__ Wc,
                                                 bf16_t* __restrict__ Wt) {
    __shared__ float tile[32][33];
    int kt = blockIdx.x * 32;
    int nt = blockIdx.y * 32;
    int tx = threadIdx.x & 31;
    int ty = threadIdx.x >> 5;
    #pragma unroll
    for (int i = 0; i < 4; i++) {
        int k = kt + ty + 8 * i;
        int n = nt + tx;
        float val = 0.f;
        if (n < P3_)      val = Wg[(size_t)k * P3_ + n];
        else if (n < NP_) val = Wc[(size_t)k * P_ + (n - P3_)];
        tile[ty + 8 * i][tx] = val;
    }
    __syncthreads();
    #pragma unroll
    for (int i = 0; i < 4; i++) {
        int n = nt + ty + 8 * i;
        int k = kt + tx;
        Wt[(size_t)n * D_ + k] = (bf16_t)tile[tx][ty + 8 * i];
    }
}

// ---- pack W_out [P][D] fp32 -> Wout^T bf16 [D][KPAD_] ----
__global__ __launch_bounds__(256) void pack_wout(const float* __restrict__ Wo,
                                                 bf16_t* __restrict__ Wt) {
    __shared__ float tile[32][33];
    int pt = blockIdx.x * 32;
    int dt = blockIdx.y * 32;
    int tx = threadIdx.x & 31;
    int ty = threadIdx.x >> 5;
    #pragma unroll
    for (int i = 0; i < 4; i++) {
        int p = pt + ty + 8 * i;
        int d = dt + tx;
        float val = (p < P_) ? Wo[(size_t)p * D_ + d] : 0.f;
        tile[ty + 8 * i][tx] = val;
    }
    __syncthreads();
    #pragma unroll
    for (int i = 0; i < 4; i++) {
        int d = dt + ty + 8 * i;
        int p = pt + tx;
        Wt[(size_t)d * KPAD_ + p] = (bf16_t)tile[tx][ty + 8 * i];
    }
}

// ---------------- 256x256 8-wave GEMM ----------------
// Per K-tile: issue all 24 ds_reads (both kk sets, named reg sets) in source
// order, then MFMA kk0 (compiler emits counted lgkmcnt(12)) then MFMA kk1
// (lgkmcnt(0), hidden under kk0's MFMAs). NO manual lgkm drains (m141 lesson).
// Memory protocol (verified r3/r4, conflicts=0): barrier; stage(t+2)->buf[cur];
// vmcnt(8) retires tile t+1's loads; barrier certifies buf[cur^1] for ALL waves.
template <int KTOT, int LDA, int LDB, int LDC, int NX, int EPI>
__global__ __launch_bounds__(512, 2) void gemm8(const bf16_t* __restrict__ A,
                                                const bf16_t* __restrict__ Bt,
                                                const float* __restrict__ res,
                                                void* __restrict__ outv) {
    constexpr int NT = KTOT / 64;
    static_assert(NT >= 4, "NT >= 4");
    __shared__ __align__(16) char smem[131072];

    const int tid  = threadIdx.x;
    const int wid  = tid >> 6;
    const int lane = tid & 63;
    const int l15  = lane & 15;
    const int sl4  = lane >> 4;
    const int sp    = sl4 ^ ((lane >> 1) & 3);          // read 16B-slot swizzle
    const int chunk = (lane & 3) ^ ((lane >> 3) & 3);   // stage-source inverse swizzle
    const int wrow = (wid >> 2) * 128;
    const int wcol = (wid & 3) * 64;

    // XCD mapping: each XCD owns 8 by-rows, iterates bx-OUTER (B-panel + 8 A-panels L2-resident)
    constexpr int MCH = (ROWS_ / 256) / 8;   // 8
    const int bid = blockIdx.x;
    const int xcd = bid & 7;
    const int idx = bid >> 3;
    const int bx  = idx / MCH;
    const int by  = xcd * MCH + (idx - bx * MCH);
    const int m0 = by * 256, n0 = bx * 256;

    const int srow = wid * 16 + (lane >> 2);
    const bf16_t* Asrc = A  + (size_t)(m0 + srow) * LDA + chunk * 8;
    const bf16_t* Bsrc = Bt + (size_t)(n0 + srow) * LDB + chunk * 8;
    const unsigned ldsA0 = (unsigned)(wid * 1024);
    const unsigned ldsB0 = 32768u + (unsigned)(wid * 1024);

    auto stage = [&](int kt, int buf) {  // 8 global_load_lds per wave
        #pragma unroll
        for (int kk = 0; kk < 2; kk++) {
            const bf16_t* sa = Asrc + kt * 64 + kk * 32;
            char* da = smem + ((unsigned)buf * 65536u + (unsigned)kk * 16384u + ldsA0);
            __builtin_amdgcn_global_load_lds((const unsigned*)sa, (unsigned*)da, 16, 0, 0);
            __builtin_amdgcn_global_load_lds((const unsigned*)(sa + (size_t)128 * LDA),
                                             (unsigned*)(da + 8192), 16, 0, 0);
            const bf16_t* sb = Bsrc + kt * 64 + kk * 32;
            char* db = smem + ((unsigned)buf * 65536u + (unsigned)kk * 16384u + ldsB0);
            __builtin_amdgcn_global_load_lds((const unsigned*)sb, (unsigned*)db, 16, 0, 0);
            __builtin_amdgcn_global_load_lds((const unsigned*)(sb + (size_t)128 * LDB),
                                             (unsigned*)(db + 8192), 16, 0, 0);
        }
    };
    auto ldA = [&](int buf, int kk, int m) -> bf16x8 {
        return *(const bf16x8*)(smem + (buf * 65536 + kk * 16384 +
                                        (wrow + m * 16 + l15) * 64 + sp * 16));
    };
    auto ldB = [&](int buf, int kk, int n) -> bf16x8 {
        return *(const bf16x8*)(smem + (buf * 65536 + 32768 + kk * 16384 +
                                        (wcol + n * 16 + l15) * 64 + sp * 16));
    };

    floatx4 acc[8][4];
    #pragma unroll
    for (int m = 0; m < 8; m++)
        #pragma unroll
        for (int n = 0; n < 4; n++) acc[m][n] = (floatx4){0.f, 0.f, 0.f, 0.f};

    bf16x8 a0[8], b0v[4], a1[8], b1v[4];

    // prologue: tiles 0,1 staged; vmcnt(8) retires tile0; barrier makes it global
    stage(0, 0);
    stage(1, 1);
    vmcnt_wait<8>();
    __builtin_amdgcn_s_barrier();

    for (int t = 0; t < NT; ++t) {
        const int c = t & 1;
        // issue ALL reads for this tile (both kk sets) before any MFMA
        #pragma unroll
        for (int m = 0; m < 8; m++) a0[m] = ldA(c, 0, m);
        #pragma unroll
        for (int n = 0; n < 4; n++) b0v[n] = ldB(c, 0, n);
        #pragma unroll
        for (int m = 0; m < 8; m++) a1[m] = ldA(c, 1, m);
        #pragma unroll
        for (int n = 0; n < 4; n++) b1v[n] = ldB(c, 1, n);

        __builtin_amdgcn_s_setprio(1);
        #pragma unroll
        for (int m = 0; m < 8; m++)
            #pragma unroll
            for (int n = 0; n < 4; n++)
                acc[m][n] = __builtin_amdgcn_mfma_f32_16x16x32_bf16(a0[m], b0v[n], acc[m][n], 0, 0, 0);
        #pragma unroll
        for (int m = 0; m < 8; m++)
            #pragma unroll
            for (int n = 0; n < 4; n++)
                acc[m][n] = __builtin_amdgcn_mfma_f32_16x16x32_bf16(a1[m], b1v[n], acc[m][n], 0, 0, 0);
        __builtin_amdgcn_s_setprio(0);

        __builtin_amdgcn_s_barrier();              // all waves done reading buf c
        if (t + 2 < NT) {
            stage(t + 2, c);                       // refill freed buffer
            vmcnt_wait<8>();                       // tile t+1's 8 loads retired (own)
        } else if (t + 2 == NT) {
            vmcnt_wait<0>();                       // certify final tile
        }
        __builtin_amdgcn_s_barrier();              // buf c^1 certified for ALL waves
    }

    const int crow = m0 + wrow + sl4 * 4;
    const int ccol = n0 + wcol + l15;
    if constexpr (EPI == 0) {
        bf16_t* O = (bf16_t*)outv;
        #pragma unroll
        for (int m = 0; m < 8; m++)
            #pragma unroll
            for (int n = 0; n < 4; n++) {
                const int col = ccol + n * 16;
                if (col < NPAD_) {
                    #pragma unroll
                    for (int r = 0; r < 4; r++) {
                        const int row = crow + m * 16 + r;
                        float g = acc[m][n][r];
                        float v = (col < P3_) ? fast_softcap_sig(g) : fast_tanh(g);
                        O[(size_t)row * LDC + col] = (bf16_t)v;
                    }
                }
            }
    } else {
        float* O = (float*)outv;
        #pragma unroll
        for (int m = 0; m < 8; m++)
            #pragma unroll
            for (int n = 0; n < 4; n++) {
                const int col = ccol + n * 16;
                #pragma unroll
                for (int r = 0; r < 4; r++) {
                    const int row = crow + m * 16 + r;
                    O[(size_t)row * LDC + col] = res[(size_t)row * LDC + col] + acc[m][n][r];
                }
            }
    }
}

// ---------------- chunked linear recurrence (r3 form) ----------------
// act layout per row (bf16, stride NPAD_): [0,P): i | [P,2P): f | [2P,3P): o | [3P,4P): tanh(c)
__global__ __launch_bounds__(256) void chunk_scan1(const bf16_t* __restrict__ act,
                                                   float* __restrict__ FA) {
    int p = blockIdx.x * 256 + threadIdx.x;
    int c = blockIdx.y;
    int b = blockIdx.z;
    if (p >= P_) return;
    const bf16_t* base = act + (size_t)(b * S_ + c * CLEN_) * NPAD_;
    float F = 1.f, Acc = 0.f;
    for (int t = 0; t < CLEN_; t++) {
        const bf16_t* r = base + (size_t)t * NPAD_;
        float iv = (float)r[p];
        float fv = (float)r[P_ + p];
        float tc = (float)r[P3_ + p];
        Acc = fv * Acc + iv * tc;
        F *= fv;
    }
    size_t idx = (((size_t)b * CHUNKS_ + c) * P_ + p) * 2;
    FA[idx]     = F;
    FA[idx + 1] = Acc;
}

__global__ __launch_bounds__(256) void chunk_scan2(const bf16_t* __restrict__ act,
                                                   const float* __restrict__ FA,
                                                   const float* __restrict__ h0,
                                                   bf16_t* __restrict__ outp) {
    int p = blockIdx.x * 256 + threadIdx.x;
    int c = blockIdx.y;
    int b = blockIdx.z;
    if (p >= KPAD_) return;
    if (p >= P_) {  // zero-fill K-pad columns for GEMM2
        bf16_t z = (bf16_t)0.f;
        for (int t = 0; t < CLEN_; t++)
            outp[(size_t)(b * S_ + c * CLEN_ + t) * KPAD_ + p] = z;
        return;
    }
    float h = h0[(size_t)b * P_ + p];
    for (int j = 0; j < c; j++) {
        size_t idx = (((size_t)b * CHUNKS_ + j) * P_ + p) * 2;
        h = FA[idx + 1] + FA[idx] * h;
    }
    const bf16_t* base = act + (size_t)(b * S_ + c * CLEN_) * NPAD_;
    bf16_t* ob = outp + (size_t)(b * S_ + c * CLEN_) * KPAD_;
    for (int t = 0; t < CLEN_; t++) {
        const bf16_t* r = base + (size_t)t * NPAD_;
        float iv = (float)r[p];
        float fv = (float)r[P_ + p];
        float ov = (float)r[2 * P_ + p];
        float tc = (float)r[P3_ + p];
        h = fv * h + iv * tc;
        ob[(size_t)t * KPAD_ + p] = (bf16_t)(ov * fast_tanh(h));
    }
}

__global__ void copy_hidden(const float* __restrict__ hs, float* __restrict__ dst) {
    int i = blockIdx.x * 256 + threadIdx.x;
    if (i < B_ * P_) dst[i] = hs[i];
}

extern "C" void kernel_launch(void* const* d_in, const int* in_sizes, int n_in,
                              void* d_out, int out_size, void* d_ws, size_t ws_size,
                              hipStream_t stream) {
    const float* x   = (const float*)d_in[0];
    const float* hs  = (const float*)d_in[1];
    const float* lnw = (const float*)d_in[2];
    const float* Wg  = (const float*)d_in[3];
    const float* Wc  = (const float*)d_in[4];
    const float* Wo  = (const float*)d_in[5];
    float* out = (float*)d_out;

    char* ws = (char*)d_ws;
    size_t off = 0;
    auto alloc = [&](size_t bytes) {
        void* p = ws + off;
        off += (bytes + 255) & ~(size_t)255;
        return p;
    };
    bf16_t* xn_outp = (bf16_t*)alloc((size_t)ROWS_ * KPAD_ * 2);   // xn then outputs
    bf16_t* act     = (bf16_t*)alloc((size_t)ROWS_ * NPAD_ * 2);
    bf16_t* WcatT   = (bf16_t*)alloc((size_t)NB_ * D_ * 2);
    bf16_t* WoutT   = (bf16_t*)alloc((size_t)D_ * KPAD_ * 2);
    float*  FA      = (float*)alloc((size_t)B_ * CHUNKS_ * P_ * 2 * 4);

    bf16_t* xn   = xn_outp;
    bf16_t* outp = xn_outp;

    hipLaunchKernelGGL(rmsnorm_kernel, dim3(ROWS_), dim3(256), 0, stream, x, lnw, xn);
    hipLaunchKernelGGL(pack_wcat, dim3(32, NB_ / 32), dim3(256), 0, stream, Wg, Wc, WcatT);
    hipLaunchKernelGGL(pack_wout, dim3(KPAD_ / 32, D_ / 32), dim3(256), 0, stream, Wo, WoutT);

    hipLaunchKernelGGL((gemm8<D_, D_, D_, NPAD_, NB_ / 256, 0>),
                       dim3((NB_ / 256) * (ROWS_ / 256)), dim3(512), 0, stream,
                       xn, WcatT, (const float*)nullptr, (void*)act);

    hipLaunchKernelGGL(chunk_scan1, dim3(6, CHUNKS_, B_), dim3(256), 0, stream, act, FA);
    hipLaunchKernelGGL(chunk_scan2, dim3(6, CHUNKS_, B_), dim3(256), 0, stream, act, FA, hs, outp);

    hipLaunchKernelGGL((gemm8<KPAD_, KPAD_, KPAD_, D_, D_ / 256, 1>),
                       dim3((D_ / 256) * (ROWS_ / 256)), dim3(512), 0, stream,
                       outp, WoutT, x, d_out);

    hipLaunchKernelGGL(copy_hidden, dim3((B_ * P_ + 255) / 256), dim3(256), 0, stream,
                       hs, out + (size_t)ROWS_ * D_);
}

// Round 6
// 463.494 us; speedup vs baseline: 1.3794x; 1.0823x over previous
//
#include <hip/hip_runtime.h>
#include <hip/hip_bf16.h>
#include <math.h>
#include <stdint.h>

typedef __bf16 bf16_t;
typedef bf16_t bf16x4 __attribute__((ext_vector_type(4)));
typedef bf16_t bf16x8 __attribute__((ext_vector_type(8)));
typedef float floatx4 __attribute__((ext_vector_type(4)));

#define B_     4
#define S_     4096
#define D_     1024
#define P_     1364
#define P3_    4092      // 3*P
#define NP_    5456      // 3P + P
#define NPAD_  5504      // act row stride
#define NB_    5632      // GEMM1 N padded to 22 tiles of 256
#define KPAD_  1408      // P_ padded (K of out-GEMM, 22 K-tiles)
#define ROWS_  16384     // B*S
#define CAP_   15.0f
#define EPS_   1e-6f
#define CHUNKS_ 32
#define CLEN_   128      // S_/CHUNKS_

// ---------------- fast transcendentals (bf16-accuracy) ----------------
__device__ __forceinline__ float fast_tanh(float x) {
    x = fminf(fmaxf(x, -15.f), 15.f);
    float e = __expf(2.f * x);
    return __fdividef(e - 1.f, e + 1.f);
}
__device__ __forceinline__ float fast_softcap_sig(float g) {
    float t = fast_tanh(g * (1.0f / CAP_));
    return __fdividef(1.f, 1.f + __expf(-CAP_ * t));
}

__device__ __forceinline__ void vmcnt0() {
    asm volatile("s_waitcnt vmcnt(0)" ::: "memory");
}

// ---------------- RMSNorm: x fp32 [ROWS][D] -> xn bf16 [ROWS][D] ----------------
__global__ __launch_bounds__(256) void rmsnorm_kernel(const float* __restrict__ x,
                                                      const float* __restrict__ w,
                                                      bf16_t* __restrict__ xn) {
    int row = blockIdx.x;
    int tid = threadIdx.x;
    const float4 v = ((const float4*)(x + (size_t)row * D_))[tid];
    float ss = v.x * v.x + v.y * v.y + v.z * v.z + v.w * v.w;
    #pragma unroll
    for (int off = 32; off > 0; off >>= 1) ss += __shfl_down(ss, off);
    __shared__ float red[4];
    if ((tid & 63) == 0) red[tid >> 6] = ss;
    __syncthreads();
    float tot = red[0] + red[1] + red[2] + red[3];
    float scale = rsqrtf(tot * (1.0f / (float)D_) + EPS_);
    const float4 wv = ((const float4*)w)[tid];
    bf16x4 o;
    o[0] = (bf16_t)(v.x * scale * wv.x);
    o[1] = (bf16_t)(v.y * scale * wv.y);
    o[2] = (bf16_t)(v.z * scale * wv.z);
    o[3] = (bf16_t)(v.w * scale * wv.w);
    ((bf16x4*)(xn + (size_t)row * D_))[tid] = o;
}

// ---- pack W_gate [D][3P] + W_cell [D][P] fp32 -> Wcat^T bf16 [NB_][D] ----
__global__ __launch_bounds__(256) void pack_wcat(const float* __restrict__ Wg,
                                                 const float* __restrict__ Wc,
                                                 bf16_t* __restrict__ Wt) {
    __shared__ float tile[32][33];
    int kt = blockIdx.x * 32;
    int nt = blockIdx.y * 32;
    int tx = threadIdx.x & 31;
    int ty = threadIdx.x >> 5;
    #pragma unroll
    for (int i = 0; i < 4; i++) {
        int k = kt + ty + 8 * i;
        int n = nt + tx;
        float val = 0.f;
        if (n < P3_)      val = Wg[(size_t)k * P3_ + n];
        else if (n < NP_) val = Wc[(size_t)k * P_ + (n - P3_)];
        tile[ty + 8 * i][tx] = val;
    }
    __syncthreads();
    #pragma unroll
    for (int i = 0; i < 4; i++) {
        int n = nt + ty + 8 * i;
        int k = kt + tx;
        Wt[(size_t)n * D_ + k] = (bf16_t)tile[tx][ty + 8 * i];
    }
}

// ---- pack W_out [P][D] fp32 -> Wout^T bf16 [D][KPAD_] ----
__global__ __launch_bounds__(256) void pack_wout(const float* __restrict__ Wo,
                                                 bf16_t* __restrict__ Wt) {
    __shared__ float tile[32][33];
    int pt = blockIdx.x * 32;
    int dt = blockIdx.y * 32;
    int tx = threadIdx.x & 31;
    int ty = threadIdx.x >> 5;
    #pragma unroll
    for (int i = 0; i < 4; i++) {
        int p = pt + ty + 8 * i;
        int d = dt + tx;
        float val = (p < P_) ? Wo[(size_t)p * D_ + d] : 0.f;
        tile[ty + 8 * i][tx] = val;
    }
    __syncthreads();
    #pragma unroll
    for (int i = 0; i < 4; i++) {
        int d = dt + ty + 8 * i;
        int p = pt + tx;
        Wt[(size_t)d * KPAD_ + p] = (bf16_t)tile[tx][ty + 8 * i];
    }
}

// ---------------- 256x256 8-wave GEMM, m201-style 4-phase per K-tile ----------------
// Per phase: {ds_reads ∥ stage} barrier; lgkmcnt(0); setprio(1); 16 MFMA; setprio(0); barrier.
// Phase reads per wave: 12 / 4 / 8 / 4 (quadrants m0-3×n0-1, m0-3×n2-3, m4-7×n2-3, m4-7×n0-1).
// Stage tile t+1 (other buffer): A-halves at ph0, B-halves at ph1; vmcnt(0) at end-of-tile
// (issued >=2.5 phases earlier -> ~free). NO sched_barrier (m141). Zero-conflict swizzle (r3).
template <int KTOT, int LDA, int LDB, int LDC, int NX, int EPI>
__global__ __launch_bounds__(512, 2) void gemm8(const bf16_t* __restrict__ A,
                                                const bf16_t* __restrict__ Bt,
                                                const float* __restrict__ res,
                                                void* __restrict__ outv) {
    constexpr int NT = KTOT / 64;
    static_assert(NT >= 2, "NT >= 2");
    __shared__ __align__(16) char smem[131072];

    const int tid  = threadIdx.x;
    const int wid  = tid >> 6;
    const int lane = tid & 63;
    const int l15  = lane & 15;
    const int sl4  = lane >> 4;
    const int sp    = sl4 ^ ((lane >> 1) & 3);          // read 16B-slot swizzle
    const int chunk = (lane & 3) ^ ((lane >> 3) & 3);   // stage-source inverse swizzle
    const int wrow = (wid >> 2) * 128;
    const int wcol = (wid & 3) * 64;

    // XCD mapping: each XCD owns 8 by-rows, iterates bx-OUTER (B-panel + A-panels L2-resident)
    constexpr int MCH = (ROWS_ / 256) / 8;   // 8
    const int bid = blockIdx.x;
    const int xcd = bid & 7;
    const int idx = bid >> 3;
    const int bx  = idx / MCH;
    const int by  = xcd * MCH + (idx - bx * MCH);
    const int m0 = by * 256, n0 = bx * 256;

    const int srow = wid * 16 + (lane >> 2);
    const bf16_t* Asrc = A  + (size_t)(m0 + srow) * LDA + chunk * 8;
    const bf16_t* Bsrc = Bt + (size_t)(n0 + srow) * LDB + chunk * 8;
    const unsigned ldsA0 = (unsigned)(wid * 1024);
    const unsigned ldsB0 = 32768u + (unsigned)(wid * 1024);

    auto stageA = [&](int kt, int buf) {   // 4 loads
        #pragma unroll
        for (int kk = 0; kk < 2; kk++) {
            const bf16_t* sa = Asrc + kt * 64 + kk * 32;
            char* da = smem + ((unsigned)buf * 65536u + (unsigned)kk * 16384u + ldsA0);
            __builtin_amdgcn_global_load_lds((const unsigned*)sa, (unsigned*)da, 16, 0, 0);
            __builtin_amdgcn_global_load_lds((const unsigned*)(sa + (size_t)128 * LDA),
                                             (unsigned*)(da + 8192), 16, 0, 0);
        }
    };
    auto stageB = [&](int kt, int buf) {   // 4 loads
        #pragma unroll
        for (int kk = 0; kk < 2; kk++) {
            const bf16_t* sb = Bsrc + kt * 64 + kk * 32;
            char* db = smem + ((unsigned)buf * 65536u + (unsigned)kk * 16384u + ldsB0);
            __builtin_amdgcn_global_load_lds((const unsigned*)sb, (unsigned*)db, 16, 0, 0);
            __builtin_amdgcn_global_load_lds((const unsigned*)(sb + (size_t)128 * LDB),
                                             (unsigned*)(db + 8192), 16, 0, 0);
        }
    };
    auto ldA = [&](int buf, int kk, int m) -> bf16x8 {
        return *(const bf16x8*)(smem + (buf * 65536 + kk * 16384 +
                                        (wrow + m * 16 + l15) * 64 + sp * 16));
    };
    auto ldB = [&](int buf, int kk, int n) -> bf16x8 {
        return *(const bf16x8*)(smem + (buf * 65536 + 32768 + kk * 16384 +
                                        (wcol + n * 16 + l15) * 64 + sp * 16));
    };

    floatx4 acc[8][4];
    #pragma unroll
    for (int m = 0; m < 8; m++)
        #pragma unroll
        for (int n = 0; n < 4; n++) acc[m][n] = (floatx4){0.f, 0.f, 0.f, 0.f};

    bf16x8 aq[8];   // A quadrant: [0..3]=kk0 m, [4..7]=kk1 m
    bf16x8 bq[4];   // B half0:    [0..1]=kk0 n0-1, [2..3]=kk1 n0-1
    bf16x8 bq2[4];  // B half1:    [0..1]=kk0 n2-3, [2..3]=kk1 n2-3

    // prologue: stage tile0 fully, drain, publish
    stageA(0, 0);
    stageB(0, 0);
    vmcnt0();
    __builtin_amdgcn_s_barrier();

    for (int t = 0; t < NT; ++t) {
        const int c = t & 1;
        const bool st = (t + 1 < NT);

        // ---- phase 0: reads m0-3 (both kk) + n0-1 (both kk) = 12; stage A(t+1)
        #pragma unroll
        for (int m = 0; m < 4; m++) { aq[m] = ldA(c, 0, m); aq[m + 4] = ldA(c, 1, m); }
        #pragma unroll
        for (int n = 0; n < 2; n++) { bq[n] = ldB(c, 0, n); bq[n + 2] = ldB(c, 1, n); }
        if (st) stageA(t + 1, c ^ 1);
        __builtin_amdgcn_s_barrier();
        asm volatile("s_waitcnt lgkmcnt(0)" ::: "memory");
        __builtin_amdgcn_s_setprio(1);
        #pragma unroll
        for (int m = 0; m < 4; m++)
            #pragma unroll
            for (int n = 0; n < 2; n++) {
                acc[m][n] = __builtin_amdgcn_mfma_f32_16x16x32_bf16(aq[m], bq[n], acc[m][n], 0, 0, 0);
                acc[m][n] = __builtin_amdgcn_mfma_f32_16x16x32_bf16(aq[m + 4], bq[n + 2], acc[m][n], 0, 0, 0);
            }
        __builtin_amdgcn_s_setprio(0);
        __builtin_amdgcn_s_barrier();

        // ---- phase 1: reads n2-3 (both kk) = 4; stage B(t+1)
        #pragma unroll
        for (int n = 0; n < 2; n++) { bq2[n] = ldB(c, 0, n + 2); bq2[n + 2] = ldB(c, 1, n + 2); }
        if (st) stageB(t + 1, c ^ 1);
        __builtin_amdgcn_s_barrier();
        asm volatile("s_waitcnt lgkmcnt(0)" ::: "memory");
        __builtin_amdgcn_s_setprio(1);
        #pragma unroll
        for (int m = 0; m < 4; m++)
            #pragma unroll
            for (int n = 0; n < 2; n++) {
                acc[m][n + 2] = __builtin_amdgcn_mfma_f32_16x16x32_bf16(aq[m], bq2[n], acc[m][n + 2], 0, 0, 0);
                acc[m][n + 2] = __builtin_amdgcn_mfma_f32_16x16x32_bf16(aq[m + 4], bq2[n + 2], acc[m][n + 2], 0, 0, 0);
            }
        __builtin_amdgcn_s_setprio(0);
        __builtin_amdgcn_s_barrier();

        // ---- phase 2: reads m4-7 (both kk) = 8
        #pragma unroll
        for (int m = 0; m < 4; m++) { aq[m] = ldA(c, 0, m + 4); aq[m + 4] = ldA(c, 1, m + 4); }
        __builtin_amdgcn_s_barrier();
        asm volatile("s_waitcnt lgkmcnt(0)" ::: "memory");
        __builtin_amdgcn_s_setprio(1);
        #pragma unroll
        for (int m = 0; m < 4; m++)
            #pragma unroll
            for (int n = 0; n < 2; n++) {
                acc[m + 4][n + 2] = __builtin_amdgcn_mfma_f32_16x16x32_bf16(aq[m], bq2[n], acc[m + 4][n + 2], 0, 0, 0);
                acc[m + 4][n + 2] = __builtin_amdgcn_mfma_f32_16x16x32_bf16(aq[m + 4], bq2[n + 2], acc[m + 4][n + 2], 0, 0, 0);
            }
        __builtin_amdgcn_s_setprio(0);
        __builtin_amdgcn_s_barrier();

        // ---- phase 3: re-read n0-1 (both kk) = 4; end-of-tile vmcnt
        #pragma unroll
        for (int n = 0; n < 2; n++) { bq[n] = ldB(c, 0, n); bq[n + 2] = ldB(c, 1, n); }
        __builtin_amdgcn_s_barrier();
        asm volatile("s_waitcnt lgkmcnt(0)" ::: "memory");
        __builtin_amdgcn_s_setprio(1);
        #pragma unroll
        for (int m = 0; m < 4; m++)
            #pragma unroll
            for (int n = 0; n < 2; n++) {
                acc[m + 4][n] = __builtin_amdgcn_mfma_f32_16x16x32_bf16(aq[m], bq[n], acc[m + 4][n], 0, 0, 0);
                acc[m + 4][n] = __builtin_amdgcn_mfma_f32_16x16x32_bf16(aq[m + 4], bq[n + 2], acc[m + 4][n], 0, 0, 0);
            }
        __builtin_amdgcn_s_setprio(0);
        vmcnt0();                      // stages issued at ph0/ph1 -> ~retired already
        __builtin_amdgcn_s_barrier();  // publish buf c^1 for tile t+1
    }

    const int crow = m0 + wrow + sl4 * 4;
    const int ccol = n0 + wcol + l15;
    if constexpr (EPI == 0) {
        bf16_t* O = (bf16_t*)outv;
        #pragma unroll
        for (int m = 0; m < 8; m++)
            #pragma unroll
            for (int n = 0; n < 4; n++) {
                const int col = ccol + n * 16;
                if (col < NPAD_) {
                    #pragma unroll
                    for (int r = 0; r < 4; r++) {
                        const int row = crow + m * 16 + r;
                        float g = acc[m][n][r];
                        float v = (col < P3_) ? fast_softcap_sig(g) : fast_tanh(g);
                        O[(size_t)row * LDC + col] = (bf16_t)v;
                    }
                }
            }
    } else {
        float* O = (float*)outv;
        #pragma unroll
        for (int m = 0; m < 8; m++)
            #pragma unroll
            for (int n = 0; n < 4; n++) {
                const int col = ccol + n * 16;
                #pragma unroll
                for (int r = 0; r < 4; r++) {
                    const int row = crow + m * 16 + r;
                    O[(size_t)row * LDC + col] = res[(size_t)row * LDC + col] + acc[m][n][r];
                }
            }
    }
}

// ---------------- chunked linear recurrence ----------------
// act layout per row (bf16, stride NPAD_): [0,P): i | [P,2P): f | [2P,3P): o | [3P,4P): tanh(c)
__global__ __launch_bounds__(256) void chunk_scan1(const bf16_t* __restrict__ act,
                                                   float* __restrict__ FA) {
    int p = blockIdx.x * 256 + threadIdx.x;
    int c = blockIdx.y;
    int b = blockIdx.z;
    if (p >= P_) return;
    const bf16_t* base = act + (size_t)(b * S_ + c * CLEN_) * NPAD_;
    float F = 1.f, Acc = 0.f;
    for (int t = 0; t < CLEN_; t++) {
        const bf16_t* r = base + (size_t)t * NPAD_;
        float iv = (float)r[p];
        float fv = (float)r[P_ + p];
        float tc = (float)r[P3_ + p];
        Acc = fv * Acc + iv * tc;
        F *= fv;
    }
    size_t idx = (((size_t)b * CHUNKS_ + c) * P_ + p) * 2;
    FA[idx]     = F;
    FA[idx + 1] = Acc;
}

__global__ __launch_bounds__(256) void chunk_scan2(const bf16_t* __restrict__ act,
                                                   const float* __restrict__ FA,
                                                   const float* __restrict__ h0,
                                                   bf16_t* __restrict__ outp) {
    int p = blockIdx.x * 256 + threadIdx.x;
    int c = blockIdx.y;
    int b = blockIdx.z;
    if (p >= KPAD_) return;
    if (p >= P_) {  // zero-fill K-pad columns for GEMM2
        bf16_t z = (bf16_t)0.f;
        for (int t = 0; t < CLEN_; t++)
            outp[(size_t)(b * S_ + c * CLEN_ + t) * KPAD_ + p] = z;
        return;
    }
    float h = h0[(size_t)b * P_ + p];
    for (int j = 0; j < c; j++) {
        size_t idx = (((size_t)b * CHUNKS_ + j) * P_ + p) * 2;
        h = FA[idx + 1] + FA[idx] * h;
    }
    const bf16_t* base = act + (size_t)(b * S_ + c * CLEN_) * NPAD_;
    bf16_t* ob = outp + (size_t)(b * S_ + c * CLEN_) * KPAD_;
    for (int t = 0; t < CLEN_; t++) {
        const bf16_t* r = base + (size_t)t * NPAD_;
        float iv = (float)r[p];
        float fv = (float)r[P_ + p];
        float ov = (float)r[2 * P_ + p];
        float tc = (float)r[P3_ + p];
        h = fv * h + iv * tc;
        ob[(size_t)t * KPAD_ + p] = (bf16_t)(ov * fast_tanh(h));
    }
}

__global__ void copy_hidden(const float* __restrict__ hs, float* __restrict__ dst) {
    int i = blockIdx.x * 256 + threadIdx.x;
    if (i < B_ * P_) dst[i] = hs[i];
}

extern "C" void kernel_launch(void* const* d_in, const int* in_sizes, int n_in,
                              void* d_out, int out_size, void* d_ws, size_t ws_size,
                              hipStream_t stream) {
    const float* x   = (const float*)d_in[0];
    const float* hs  = (const float*)d_in[1];
    const float* lnw = (const float*)d_in[2];
    const float* Wg  = (const float*)d_in[3];
    const float* Wc  = (const float*)d_in[4];
    const float* Wo  = (const float*)d_in[5];
    float* out = (float*)d_out;

    char* ws = (char*)d_ws;
    size_t off = 0;
    auto alloc = [&](size_t bytes) {
        void* p = ws + off;
        off += (bytes + 255) & ~(size_t)255;
        return p;
    };
    bf16_t* xn_outp = (bf16_t*)alloc((size_t)ROWS_ * KPAD_ * 2);   // xn then outputs
    bf16_t* act     = (bf16_t*)alloc((size_t)ROWS_ * NPAD_ * 2);
    bf16_t* WcatT   = (bf16_t*)alloc((size_t)NB_ * D_ * 2);
    bf16_t* WoutT   = (bf16_t*)alloc((size_t)D_ * KPAD_ * 2);
    float*  FA      = (float*)alloc((size_t)B_ * CHUNKS_ * P_ * 2 * 4);

    bf16_t* xn   = xn_outp;
    bf16_t* outp = xn_outp;

    hipLaunchKernelGGL(rmsnorm_kernel, dim3(ROWS_), dim3(256), 0, stream, x, lnw, xn);
    hipLaunchKernelGGL(pack_wcat, dim3(32, NB_ / 32), dim3(256), 0, stream, Wg, Wc, WcatT);
    hipLaunchKernelGGL(pack_wout, dim3(KPAD_ / 32, D_ / 32), dim3(256), 0, stream, Wo, WoutT);

    hipLaunchKernelGGL((gemm8<D_, D_, D_, NPAD_, NB_ / 256, 0>),
                       dim3((NB_ / 256) * (ROWS_ / 256)), dim3(512), 0, stream,
                       xn, WcatT, (const float*)nullptr, (void*)act);

    hipLaunchKernelGGL(chunk_scan1, dim3(6, CHUNKS_, B_), dim3(256), 0, stream, act, FA);
    hipLaunchKernelGGL(chunk_scan2, dim3(6, CHUNKS_, B_), dim3(256), 0, stream, act, FA, hs, outp);

    hipLaunchKernelGGL((gemm8<KPAD_, KPAD_, KPAD_, D_, D_ / 256, 1>),
                       dim3((D_ / 256) * (ROWS_ / 256)), dim3(512), 0, stream,
                       outp, WoutT, x, d_out);

    hipLaunchKernelGGL(copy_hidden, dim3((B_ * P_ + 255) / 256), dim3(256), 0, stream,
                       hs, out + (size_t)ROWS_ * D_);
}